// Round 4
// baseline (478.243 us; speedup 1.0000x reference)
//
#include <hip/hip_runtime.h>

// GAT layer, N=8192, F_IN=512, F_OUT=256. ALL tensors f32; adj int32.
// out = softmax_row(mask(leaky(s1_i+s2_j))) @ h, h = X@W, s{1,2} = h_f32@a{1,2}.
//
// R13 -> R14:
//  * Theory: attn (~109us) is convoy-bound: ONE 8-wave barrier group per CU
//    (VGPR>128 -> 2 waves/SIMD -> exactly 1 block resident). All waves stall
//    together at each barrier/L2 hand-off; ~4000cyc/iter vs ~1500cyc of work.
//  * attn now 16 rows x 256 thr (4 waves), grid 512 -> TWO co-resident blocks
//    per CU with independent barriers; each fills the other's stalls.
//    Per-thread work/partition identical (numerics bit-identical canary).
//  * B frags single-buffered (VGPR budget); calcP placed before MFMA cluster
//    covers B's L2 latency. Cost: hTt L2 traffic 1->2 GB (~53% L2 ceiling, ok).

typedef __attribute__((ext_vector_type(8))) short bf16x8;
typedef __attribute__((ext_vector_type(4))) float fx4;
typedef __attribute__((ext_vector_type(4))) int ix4;
typedef __attribute__((ext_vector_type(2))) unsigned int ux2;

#define NN 8192
#define FIN 512
#define FOUT 256
#define PS 136     // LDS P row stride (shorts); 272B stride -> conflict-free b128
#define AROWS 16   // attn rows per block (2 blocks/CU for independent barriers)

__device__ __forceinline__ unsigned short f2bf(float f) {
    unsigned int x = __float_as_uint(f);
    x += 0x7fffu + ((x >> 16) & 1u);
    return (unsigned short)(x >> 16);
}
__device__ __forceinline__ bf16x8 pack8(fx4 a, fx4 b) {
    bf16x8 r;
    r[0] = (short)f2bf(a[0]); r[1] = (short)f2bf(a[1]);
    r[2] = (short)f2bf(a[2]); r[3] = (short)f2bf(a[3]);
    r[4] = (short)f2bf(b[0]); r[5] = (short)f2bf(b[1]);
    r[6] = (short)f2bf(b[2]); r[7] = (short)f2bf(b[3]);
    return r;
}

// ---------- kernel 0: WTt[((k>>5)*256+c)*32 + (k&31)] = bf16(W[k][c]) ----------
__global__ void wt_kernel(const float* __restrict__ W,
                          unsigned short* __restrict__ WTt) {
    const int c = threadIdx.x;
    const int k = blockIdx.x;
    WTt[((size_t)(k >> 5) * 256 + c) * 32 + (k & 31)] = f2bf(W[k * FOUT + c]);
}

// ---------- kernel 1: h-tile (MFMA) + fused s1/s2 ----------
// 512 blocks x 16 rows. MFMA 16x16x32: A[m=l&15][k=q*8+j], B[k=q*8+j][n=l&15],
// D: col=l&15, row=q*4+r.
__global__ __launch_bounds__(256) void prep_kernel(
    const float* __restrict__ X,              // 8192x512 f32
    const unsigned short* __restrict__ WTt,   // tiled 256x512 bf16
    const float* __restrict__ A,              // 512 f32 (a1|a2)
    unsigned short* __restrict__ hTt,         // tiled 256x8192 bf16
    float* __restrict__ s1, float* __restrict__ s2)
{
    __shared__ float s1sh[4][16], s2sh[4][16];
    const int tid = threadIdx.x;

    const int w = tid >> 6, l = tid & 63, q = l >> 4, lr = l & 15;
    const int r0 = blockIdx.x * 16;
    const int cbase = w * 64;
    fx4 acc[4] = {};

    for (int kb = 0; kb < FIN; kb += 32) {
        const float* xp = X + (size_t)(r0 + lr) * FIN + kb + q * 8;
        bf16x8 a0 = pack8(*(const fx4*)xp, *(const fx4*)(xp + 4));
#pragma unroll
        for (int tc = 0; tc < 4; ++tc) {
            bf16x8 b = *(const bf16x8*)(WTt + ((size_t)(kb >> 5) * 256 + cbase + tc * 16 + lr) * 32 + q * 8);
            acc[tc] = __builtin_amdgcn_mfma_f32_16x16x32_bf16(a0, b, acc[tc], 0, 0, 0);
        }
    }

    // tiled hTt write
    const int jb = r0 >> 5, jo = (r0 & 31) + q * 4;
#pragma unroll
    for (int tc = 0; tc < 4; ++tc) {
        const int c = cbase + tc * 16 + lr;
        ux2 hp;
        hp.x = (unsigned)f2bf(acc[tc][0]) | ((unsigned)f2bf(acc[tc][1]) << 16);
        hp.y = (unsigned)f2bf(acc[tc][2]) | ((unsigned)f2bf(acc[tc][3]) << 16);
        *(ux2*)(hTt + ((size_t)jb * 256 + c) * 32 + jo) = hp;
    }

    // fused s1/s2 from f32 accumulators
    float p1[4] = {}, p2[4] = {};
#pragma unroll
    for (int tc = 0; tc < 4; ++tc) {
        const int c = cbase + tc * 16 + lr;
        const float a1v = A[c], a2v = A[FOUT + c];
#pragma unroll
        for (int r = 0; r < 4; ++r) {
            p1[r] += acc[tc][r] * a1v;
            p2[r] += acc[tc][r] * a2v;
        }
    }
#pragma unroll
    for (int r = 0; r < 4; ++r) {
#pragma unroll
        for (int off = 1; off < 16; off <<= 1) {
            p1[r] += __shfl_xor(p1[r], off);
            p2[r] += __shfl_xor(p2[r], off);
        }
        if (lr == 0) { s1sh[w][q * 4 + r] = p1[r]; s2sh[w][q * 4 + r] = p2[r]; }
    }
    __syncthreads();
    if (tid < 16) {
        s1[r0 + tid] = s1sh[0][tid] + s1sh[1][tid] + s1sh[2][tid] + s1sh[3][tid];
        s2[r0 + tid] = s2sh[0][tid] + s2sh[1][tid] + s2sh[2][tid] + s2sh[3][tid];
    }
}

// ---------- kernel 2: fused masked-softmax @ h, f32 out ----------
// Grid 512 x 256 thr. 16 rows/block; wave w owns cols w*64..+63 (tc 0..3).
// 2 blocks/CU co-resident -> independent barrier groups interleave.
// adj streamed directly (nt loads, 32 B/thread/iter, 2 iters ahead);
// B-frags (hTt, L2) single-buffered, latency covered by calcP + sibling block;
// P (16x128 bf16) double-buffered in LDS; in-loop barrier drains ONLY lgkmcnt.
__global__ __launch_bounds__(256) void attn_kernel(
    const int* __restrict__ adj,             // 8192 x 8192 i32
    const unsigned short* __restrict__ hTt,  // tiled 256 x 8192 bf16
    const float* __restrict__ s1,
    const float* __restrict__ s2,
    float* __restrict__ out)                 // 8192 x 256 f32
{
    __shared__ unsigned short P[2][AROWS * PS];   // 8.7 KB
    __shared__ float dsh[AROWS];

    const int tid = threadIdx.x;
    const int r0 = blockIdx.x * AROWS;

    // P-generation role: thread -> (row, 8-col group)
    const int prow = tid >> 4;                 // 0..15
    const int pq = tid & 15;                   // cols pq*8..+7
    const float s1v = s1[r0 + prow];
    const int* arow = adj + (size_t)(r0 + prow) * NN + pq * 8;
    float denp = 0.f;

    // MFMA role: 4 waves, wave w owns cols w*64..w*64+63 (4 tc frags)
    const int w = tid >> 6, l = tid & 63, q = l >> 4, lr = l & 15;
    const int cbase = w * 64;
    fx4 acc[4] = {};

    struct LSet { ix4 v0, v1; fx4 s2a, s2b; };
    LSet LA, LB;
    bf16x8 B[4][4];                            // [ks][tc], single-buffered

    auto loadP = [&](int kt, LSet& L) {
        const int* ap = arow + kt * 128;
        L.v0 = __builtin_nontemporal_load((const ix4*)ap);       // nt: keep the
        L.v1 = __builtin_nontemporal_load((const ix4*)(ap + 4)); // stream out of L2
        L.s2a = *(const fx4*)(s2 + kt * 128 + pq * 8);
        L.s2b = *(const fx4*)(s2 + kt * 128 + pq * 8 + 4);
    };
    auto calcP = [&](int b, const LSet& L) {
        bf16x8 pv;
#pragma unroll
        for (int j = 0; j < 8; ++j) {
            const int aj = (j < 4) ? L.v0[j] : L.v1[j - 4];
            const float s2j = (j < 4) ? L.s2a[j] : L.s2b[j - 4];
            float t = s1v + s2j;
            float e = fmaxf(t, 0.2f * t);      // leaky_relu, alpha=0.2
            e = fminf(e, 30.f);                // overflow guard (inactive)
            const float p = (aj != 0) ? __expf(e) : 0.f;
            denp += p;
            pv[j] = (short)f2bf(p);
        }
        *(bf16x8*)(&P[b][prow * PS + pq * 8]) = pv;   // 16B store
    };
    auto loadB = [&](int it) {
#pragma unroll
        for (int ks = 0; ks < 4; ++ks)
#pragma unroll
            for (int tc = 0; tc < 4; ++tc)
                B[ks][tc] = *(const bf16x8*)(hTt + ((size_t)(it * 4 + ks) * 256 + cbase + tc * 16 + lr) * 32 + q * 8);
    };

    // LDS-only barrier: ds_writes drained (lgkmcnt), global loads stay in flight.
    auto ldsBarrier = [&]() {
        asm volatile("s_waitcnt lgkmcnt(0)" ::: "memory");
        __builtin_amdgcn_s_barrier();
    };

    const int ITERS = NN / 128;   // 64
    loadP(0, LA);
    calcP(0, LA);                 // writes P[0]
    loadP(1, LA);
    ldsBarrier();

    auto body = [&](int it, LSet& Lc, LSet& Ln) {
        loadB(it);                                 // single-buffer: issue first
        if (it + 2 < ITERS) loadP(it + 2, Ln);     // 2-deep (HBM adj stream)
        const unsigned short* Pb = P[it & 1];
        bf16x8 af0[4];
#pragma unroll
        for (int ks = 0; ks < 4; ++ks)
            af0[ks] = *(const bf16x8*)(Pb + lr * PS + ks * 32 + q * 8);
        if (it + 1 < ITERS) calcP((it + 1) & 1, Lc);  // covers B's L2 latency
        __builtin_amdgcn_s_setprio(1);
#pragma unroll
        for (int ks = 0; ks < 4; ++ks)
#pragma unroll
            for (int tc = 0; tc < 4; ++tc)
                acc[tc] = __builtin_amdgcn_mfma_f32_16x16x32_bf16(af0[ks], B[ks][tc], acc[tc], 0, 0, 0);
        __builtin_amdgcn_s_setprio(0);
        ldsBarrier();
    };

    for (int it = 0; it < ITERS; it += 2) {
        body(it, LA, LB);
        body(it + 1, LB, LA);
    }

    // den: reduce over the 16 lanes sharing a row
    float v = denp;
    v += __shfl_xor(v, 1);
    v += __shfl_xor(v, 2);
    v += __shfl_xor(v, 4);
    v += __shfl_xor(v, 8);
    if (pq == 0) dsh[prow] = v;
    __syncthreads();

#pragma unroll
    for (int r = 0; r < 4; ++r) {
        const int row = q * 4 + r;
        const float dinv = 1.0f / fmaxf(dsh[row], 1e-30f);
#pragma unroll
        for (int tc = 0; tc < 4; ++tc) {
            out[(size_t)(r0 + row) * FOUT + cbase + tc * 16 + lr] = acc[tc][r] * dinv;
        }
    }
}

extern "C" void kernel_launch(void* const* d_in, const int* in_sizes, int n_in,
                              void* d_out, int out_size, void* d_ws, size_t ws_size,
                              hipStream_t stream) {
    const float *X = nullptr, *W = nullptr, *A = nullptr;
    const int* adj = nullptr;
    for (int i = 0; i < n_in; ++i) {
        switch (in_sizes[i]) {
            case NN * FIN:   X = (const float*)d_in[i]; break;
            case FIN * FOUT: W = (const float*)d_in[i]; break;
            case 2 * FOUT:   A = (const float*)d_in[i]; break;
            case NN * NN:    adj = (const int*)d_in[i]; break;
        }
    }
    if (!X) X = (const float*)d_in[0];
    if (!W) W = (const float*)d_in[1];
    if (!A) A = (const float*)d_in[2];
    if (!adj) adj = (const int*)d_in[3];
    float* out = (float*)d_out;

    // ws layout (subset of the 1 GiB ws):
    char* ws = (char*)d_ws;
    float* s1 = (float*)ws;                                 // 32 KB
    float* s2 = (float*)(ws + 32768);                       // 32 KB
    unsigned short* WTt = (unsigned short*)(ws + 98304);    // 256 KB
    unsigned short* hTt = (unsigned short*)(ws + 360448);   // 4 MB

    wt_kernel<<<512, 256, 0, stream>>>(W, WTt);
    prep_kernel<<<512, 256, 0, stream>>>(X, WTt, A, hTt, s1, s2);
    attn_kernel<<<NN / AROWS, 256, 0, stream>>>(adj, hTt, s1, s2, out);
}

// Round 5
// 439.135 us; speedup vs baseline: 1.0891x; 1.0891x over previous
//
#include <hip/hip_runtime.h>

// GAT layer, N=8192, F_IN=512, F_OUT=256. ALL tensors f32; adj int32.
// out = softmax_row(mask(leaky(s1_i+s2_j))) @ h, h = X@W, s{1,2} = h_f32@a{1,2}.
//
// R14 -> R15:
//  * R14 counters: attn is STALL-bound (Mfma 8%, VALU 19%, HBM 12%, occ 19%).
//    2-blocks/CU doubled per-CU B volume + single-buffer B exposed L2 latency
//    -> revert to R13 geometry (256 blocks x 512 thr, 8 waves, B dbuf 1-ahead).
//  * New: break the per-iter P convoy. P ring NBUF=4; calcP at body j produces
//    P for iter j+2 (D=2); barrier every S=2 bodies (32 barriers, was 64).
//    Hazards: D>=S (write->read straddles barrier), NBUF>=D+S (no clobber),
//    ldsBarrier's lgkmcnt(0) makes reads complete before signaling. Unroll x4
//    for static ring-slot naming. adj/s2 prefetch 4 ahead (LSet ring of 4).
//  * calcP order per thread still kt=0..63 -> bit-identical numerics (canary).

typedef __attribute__((ext_vector_type(8))) short bf16x8;
typedef __attribute__((ext_vector_type(4))) float fx4;
typedef __attribute__((ext_vector_type(4))) int ix4;
typedef __attribute__((ext_vector_type(2))) unsigned int ux2;

#define NN 8192
#define FIN 512
#define FOUT 256
#define PS 136     // LDS P row stride (shorts); 272B stride -> conflict-free b128
#define AROWS 32   // attn rows per block

__device__ __forceinline__ unsigned short f2bf(float f) {
    unsigned int x = __float_as_uint(f);
    x += 0x7fffu + ((x >> 16) & 1u);
    return (unsigned short)(x >> 16);
}
__device__ __forceinline__ bf16x8 pack8(fx4 a, fx4 b) {
    bf16x8 r;
    r[0] = (short)f2bf(a[0]); r[1] = (short)f2bf(a[1]);
    r[2] = (short)f2bf(a[2]); r[3] = (short)f2bf(a[3]);
    r[4] = (short)f2bf(b[0]); r[5] = (short)f2bf(b[1]);
    r[6] = (short)f2bf(b[2]); r[7] = (short)f2bf(b[3]);
    return r;
}

// ---------- kernel 0: WTt[((k>>5)*256+c)*32 + (k&31)] = bf16(W[k][c]) ----------
__global__ void wt_kernel(const float* __restrict__ W,
                          unsigned short* __restrict__ WTt) {
    const int c = threadIdx.x;
    const int k = blockIdx.x;
    WTt[((size_t)(k >> 5) * 256 + c) * 32 + (k & 31)] = f2bf(W[k * FOUT + c]);
}

// ---------- kernel 1: h-tile (MFMA) + fused s1/s2 ----------
// 512 blocks x 16 rows. MFMA 16x16x32: A[m=l&15][k=q*8+j], B[k=q*8+j][n=l&15],
// D: col=l&15, row=q*4+r.
__global__ __launch_bounds__(256) void prep_kernel(
    const float* __restrict__ X,              // 8192x512 f32
    const unsigned short* __restrict__ WTt,   // tiled 256x512 bf16
    const float* __restrict__ A,              // 512 f32 (a1|a2)
    unsigned short* __restrict__ hTt,         // tiled 256x8192 bf16
    float* __restrict__ s1, float* __restrict__ s2)
{
    __shared__ float s1sh[4][16], s2sh[4][16];
    const int tid = threadIdx.x;

    const int w = tid >> 6, l = tid & 63, q = l >> 4, lr = l & 15;
    const int r0 = blockIdx.x * 16;
    const int cbase = w * 64;
    fx4 acc[4] = {};

    for (int kb = 0; kb < FIN; kb += 32) {
        const float* xp = X + (size_t)(r0 + lr) * FIN + kb + q * 8;
        bf16x8 a0 = pack8(*(const fx4*)xp, *(const fx4*)(xp + 4));
#pragma unroll
        for (int tc = 0; tc < 4; ++tc) {
            bf16x8 b = *(const bf16x8*)(WTt + ((size_t)(kb >> 5) * 256 + cbase + tc * 16 + lr) * 32 + q * 8);
            acc[tc] = __builtin_amdgcn_mfma_f32_16x16x32_bf16(a0, b, acc[tc], 0, 0, 0);
        }
    }

    // tiled hTt write
    const int jb = r0 >> 5, jo = (r0 & 31) + q * 4;
#pragma unroll
    for (int tc = 0; tc < 4; ++tc) {
        const int c = cbase + tc * 16 + lr;
        ux2 hp;
        hp.x = (unsigned)f2bf(acc[tc][0]) | ((unsigned)f2bf(acc[tc][1]) << 16);
        hp.y = (unsigned)f2bf(acc[tc][2]) | ((unsigned)f2bf(acc[tc][3]) << 16);
        *(ux2*)(hTt + ((size_t)jb * 256 + c) * 32 + jo) = hp;
    }

    // fused s1/s2 from f32 accumulators
    float p1[4] = {}, p2[4] = {};
#pragma unroll
    for (int tc = 0; tc < 4; ++tc) {
        const int c = cbase + tc * 16 + lr;
        const float a1v = A[c], a2v = A[FOUT + c];
#pragma unroll
        for (int r = 0; r < 4; ++r) {
            p1[r] += acc[tc][r] * a1v;
            p2[r] += acc[tc][r] * a2v;
        }
    }
#pragma unroll
    for (int r = 0; r < 4; ++r) {
#pragma unroll
        for (int off = 1; off < 16; off <<= 1) {
            p1[r] += __shfl_xor(p1[r], off);
            p2[r] += __shfl_xor(p2[r], off);
        }
        if (lr == 0) { s1sh[w][q * 4 + r] = p1[r]; s2sh[w][q * 4 + r] = p2[r]; }
    }
    __syncthreads();
    if (tid < 16) {
        s1[r0 + tid] = s1sh[0][tid] + s1sh[1][tid] + s1sh[2][tid] + s1sh[3][tid];
        s2[r0 + tid] = s2sh[0][tid] + s2sh[1][tid] + s2sh[2][tid] + s2sh[3][tid];
    }
}

// ---------- kernel 2: fused masked-softmax @ h, f32 out ----------
// Grid 256 x 512 thr. 32 rows/block; wave w owns cols w*32..+31.
// P ring: NBUF=4 LDS buffers; body j reads P[j&3], calcP writes P[(j+2)&3]
// (produced 2 iters ahead); barrier (lgkm-only) every 2 bodies.
// B-frags (hTt, L2) double-buffered 1 body ahead; adj nt-streamed 4 ahead.
__global__ __launch_bounds__(512) void attn_kernel(
    const int* __restrict__ adj,             // 8192 x 8192 i32
    const unsigned short* __restrict__ hTt,  // tiled 256 x 8192 bf16
    const float* __restrict__ s1,
    const float* __restrict__ s2,
    float* __restrict__ out)                 // 8192 x 256 f32
{
    __shared__ unsigned short P[4][AROWS * PS];   // 34.8 KB ring
    __shared__ float dsh[AROWS];

    const int tid = threadIdx.x;
    const int r0 = blockIdx.x * AROWS;

    // P-generation role: thread -> (row, 8-col group)
    const int prow = tid >> 4;                 // 0..31
    const int pq = tid & 15;                   // cols pq*8..+7
    const float s1v = s1[r0 + prow];
    const int* arow = adj + (size_t)(r0 + prow) * NN + pq * 8;
    float denp = 0.f;

    // MFMA role
    const int w = tid >> 6, l = tid & 63, q = l >> 4, lr = l & 15;
    const int cbase = w * 32;
    fx4 acc[2][2] = {};

    struct LSet { ix4 v0, v1; fx4 s2a, s2b; };
    LSet S0, S1, S2, S3;                       // ring slot = kt & 3
    bf16x8 B0[4][2], B1[4][2];

    auto loadP = [&](int kt, LSet& L) {
        const int* ap = arow + kt * 128;
        L.v0 = __builtin_nontemporal_load((const ix4*)ap);       // nt: keep the
        L.v1 = __builtin_nontemporal_load((const ix4*)(ap + 4)); // stream out of L2
        L.s2a = *(const fx4*)(s2 + kt * 128 + pq * 8);
        L.s2b = *(const fx4*)(s2 + kt * 128 + pq * 8 + 4);
    };
    auto calcP = [&](int b, const LSet& L) {   // writes P[b]
        bf16x8 pv;
#pragma unroll
        for (int j = 0; j < 8; ++j) {
            const int aj = (j < 4) ? L.v0[j] : L.v1[j - 4];
            const float s2j = (j < 4) ? L.s2a[j] : L.s2b[j - 4];
            float t = s1v + s2j;
            float e = fmaxf(t, 0.2f * t);      // leaky_relu, alpha=0.2
            e = fminf(e, 30.f);                // overflow guard (inactive)
            const float p = (aj != 0) ? __expf(e) : 0.f;
            denp += p;
            pv[j] = (short)f2bf(p);
        }
        *(bf16x8*)(&P[b][prow * PS + pq * 8]) = pv;   // 16B store
    };
    auto loadB = [&](int it, bf16x8 (&B)[4][2]) {
#pragma unroll
        for (int ks = 0; ks < 4; ++ks)
#pragma unroll
            for (int tc = 0; tc < 2; ++tc)
                B[ks][tc] = *(const bf16x8*)(hTt + ((size_t)(it * 4 + ks) * 256 + cbase + tc * 16 + lr) * 32 + q * 8);
    };

    // LDS-only barrier: ds ops drained (lgkmcnt), global loads stay in flight.
    auto ldsBarrier = [&]() {
        asm volatile("s_waitcnt lgkmcnt(0)" ::: "memory");
        __builtin_amdgcn_s_barrier();
    };

    const int ITERS = NN / 128;   // 64

    // prologue: LSets kt=0..3 into slots 0..3; P[0],P[1] written; B(0) in flight
    loadP(0, S0); loadP(1, S1); loadP(2, S2); loadP(3, S3);
    calcP(0, S0);                 // kt=0 -> P[0]
    calcP(1, S1);                 // kt=1 -> P[1]
    loadB(0, B0);
    ldsBarrier();

    // body j: reads P[j&3]; calcP for kt=j+2 -> P[(j+2)&3]; loads LSet kt=j+4
    // into slot j&3; B for body j+1 into Bn; barrier only when bar==true.
    auto body = [&](int j, bf16x8 (&Bc)[4][2], bf16x8 (&Bn)[4][2],
                    LSet& Scons, LSet& Sload, bool bar) {
        if (j + 1 < ITERS) loadB(j + 1, Bn);       // in flight across barrier
        if (j + 4 < ITERS) loadP(j + 4, Sload);    // 4-deep adj/s2 stream
        const unsigned short* Pb = P[j & 3];
        bf16x8 af0[4], af1[4];
#pragma unroll
        for (int ks = 0; ks < 4; ++ks) {
            af0[ks] = *(const bf16x8*)(Pb + lr * PS + ks * 32 + q * 8);
            af1[ks] = *(const bf16x8*)(Pb + (16 + lr) * PS + ks * 32 + q * 8);
        }
        if (j + 2 < ITERS) calcP((j + 2) & 3, Scons);  // off the critical path
        __builtin_amdgcn_s_setprio(1);
#pragma unroll
        for (int ks = 0; ks < 4; ++ks)
#pragma unroll
            for (int tc = 0; tc < 2; ++tc) {
                acc[0][tc] = __builtin_amdgcn_mfma_f32_16x16x32_bf16(af0[ks], Bc[ks][tc], acc[0][tc], 0, 0, 0);
                acc[1][tc] = __builtin_amdgcn_mfma_f32_16x16x32_bf16(af1[ks], Bc[ks][tc], acc[1][tc], 0, 0, 0);
            }
        __builtin_amdgcn_s_setprio(0);
        if (bar) ldsBarrier();
    };

    for (int it = 0; it < ITERS; it += 4) {
        body(it + 0, B0, B1, S2, S0, false);   // consume kt=it+2 (slot 2), load kt=it+4 (slot 0)
        body(it + 1, B1, B0, S3, S1, true);    // consume slot 3, load slot 1, barrier
        body(it + 2, B0, B1, S0, S2, false);   // consume slot 0, load slot 2
        body(it + 3, B1, B0, S1, S3, true);    // consume slot 1, load slot 3, barrier
    }

    // den: reduce over the 16 lanes sharing a row
    float v = denp;
    v += __shfl_xor(v, 1);
    v += __shfl_xor(v, 2);
    v += __shfl_xor(v, 4);
    v += __shfl_xor(v, 8);
    if (pq == 0) dsh[prow] = v;
    __syncthreads();

#pragma unroll
    for (int mg = 0; mg < 2; ++mg) {
#pragma unroll
        for (int r = 0; r < 4; ++r) {
            const int row = mg * 16 + q * 4 + r;
            const float dinv = 1.0f / fmaxf(dsh[row], 1e-30f);
#pragma unroll
            for (int tc = 0; tc < 2; ++tc) {
                out[(size_t)(r0 + row) * FOUT + cbase + tc * 16 + lr] = acc[mg][tc][r] * dinv;
            }
        }
    }
}

extern "C" void kernel_launch(void* const* d_in, const int* in_sizes, int n_in,
                              void* d_out, int out_size, void* d_ws, size_t ws_size,
                              hipStream_t stream) {
    const float *X = nullptr, *W = nullptr, *A = nullptr;
    const int* adj = nullptr;
    for (int i = 0; i < n_in; ++i) {
        switch (in_sizes[i]) {
            case NN * FIN:   X = (const float*)d_in[i]; break;
            case FIN * FOUT: W = (const float*)d_in[i]; break;
            case 2 * FOUT:   A = (const float*)d_in[i]; break;
            case NN * NN:    adj = (const int*)d_in[i]; break;
        }
    }
    if (!X) X = (const float*)d_in[0];
    if (!W) W = (const float*)d_in[1];
    if (!A) A = (const float*)d_in[2];
    if (!adj) adj = (const int*)d_in[3];
    float* out = (float*)d_out;

    // ws layout (subset of the 1 GiB ws):
    char* ws = (char*)d_ws;
    float* s1 = (float*)ws;                                 // 32 KB
    float* s2 = (float*)(ws + 32768);                       // 32 KB
    unsigned short* WTt = (unsigned short*)(ws + 98304);    // 256 KB
    unsigned short* hTt = (unsigned short*)(ws + 360448);   // 4 MB

    wt_kernel<<<512, 256, 0, stream>>>(W, WTt);
    prep_kernel<<<512, 256, 0, stream>>>(X, WTt, A, hTt, s1, s2);
    attn_kernel<<<NN / AROWS, 512, 0, stream>>>(adj, hTt, s1, s2, out);
}